// Round 5
// baseline (290.018 us; speedup 1.0000x reference)
//
#include <hip/hip_runtime.h>
#include <math.h>

#define NUM_EMB 1024
#define EMB_DIM 256
#define NROWS   65536
#define NTHREADS 256
#define MTHREADS 1024
#define EPSF 1.5e-3f
#define GCAP 458752
#define LLCAP 3837

// out layout (float32, concatenated):
#define OFF_IDX  16777216
#define OFF_VQ   16842752

// ws layout (bytes):
#define WS_C2    0         // float[1024]  ||e_k||^2 sequential fp32 (verified)
#define WS_HIST  4096      // int[1024]
#define WS_LOSS  8192      // float
#define WS_GCNT  8196      // int
#define WS_R2    8448      // float[65536] numpy-pairwise ||z_n||^2 (verified)
#define WS_SLOT  270592    // ull[65536]  packed (dist_bits<<32)|k
#define WS_ETF   794880    // float[1024][256]  emb^T fp32
#define WS_ETB   1843456   // ushort[1024][256] emb^T bf16
#define WS_RMIN  2367744   // int[65536]  bf16 running row-min bits (block-private rows)
#define WS_GLIST 2629888   // uint[GCAP] packed (row<<10)|k

typedef __attribute__((ext_vector_type(8))) short bf16x8;
typedef __attribute__((ext_vector_type(4))) float f32x4;

// lgkm-only barrier: orders all LDS ops across the block WITHOUT draining the
// global-load queue (vmcnt), so register prefetches ride across. Memory
// clobbers fence compiler reordering on both sides (rule 18).
#define BAR_LGKM() do {                                        \
    asm volatile("s_waitcnt lgkmcnt(0)" ::: "memory");         \
    __builtin_amdgcn_s_barrier();                              \
    asm volatile("" ::: "memory");                             \
  } while (0)

__device__ __forceinline__ unsigned short f2bf(float x) {
  unsigned u = __float_as_uint(x);
  unsigned r = (u + 0x7FFFu + ((u >> 16) & 1u)) >> 16;
  return (unsigned short)r;
}

// merged: c2 prep (blocks 0..3) + transpose (blocks 4..67)
__global__ __launch_bounds__(NTHREADS) void vq_pt(
    const float* __restrict__ emb, float* __restrict__ cvec,
    int* __restrict__ hist, float* __restrict__ loss, int* __restrict__ gcnt,
    float* __restrict__ embTf, unsigned short* __restrict__ embTbf) {
  __shared__ float t[64][65];
  const int tid = threadIdx.x;
  if (blockIdx.x < 4) {
    // c2[k] = sequential fp32 sum of fl(e[d,k]^2)  [verified round 3]
    int k = blockIdx.x * NTHREADS + tid;
    float s = 0.f;
    for (int d = 0; d < EMB_DIM; ++d) {
      float v = emb[d * NUM_EMB + k];
      s = __fadd_rn(s, __fmul_rn(v, v));
    }
    cvec[k] = s;
    hist[k] = 0;
    if (k == 0) { *loss = 0.f; *gcnt = 0; }
  } else {
    // transpose emb [256][1024] -> embTf fp32 [1024][256] + embTbf bf16
    const int b = blockIdx.x - 4;
    const int kt = b & 15, dt = b >> 4;
    #pragma unroll
    for (int it = 0; it < 16; ++it) {
      int i = tid + it * NTHREADS, r = i >> 6, c = i & 63;
      t[r][c] = emb[(dt * 64 + r) * NUM_EMB + kt * 64 + c];
    }
    __syncthreads();
    #pragma unroll
    for (int it = 0; it < 16; ++it) {
      int i = tid + it * NTHREADS, r = i >> 6, c = i & 63;
      float v = t[c][r];
      embTf[(kt * 64 + r) * EMB_DIM + dt * 64 + c] = v;
      embTbf[(kt * 64 + r) * EMB_DIM + dt * 64 + c] = f2bf(v);
    }
  }
}

// r2[n] = numpy pairwise fp32 sum of z[n,:]**2  [verified round 3, verbatim]
__global__ __launch_bounds__(NTHREADS) void vq_r2k(
    const float* __restrict__ z, float* __restrict__ r2out) {
  __shared__ float zc[64][36];
  __shared__ float pmm[64][2][4];
  const int tid = threadIdx.x;
  const int n0 = blockIdx.x * 64;
  const float* zrow = z + (size_t)n0 * EMB_DIM;
  const int prow = tid >> 2, pm = tid & 3;
  float racc[2][2] = {{0.f, 0.f}, {0.f, 0.f}};
  for (int dc = 0; dc < 8; ++dc) {
    __syncthreads();
    #pragma unroll
    for (int it = 0; it < 2; ++it) {
      int i = tid + it * NTHREADS, row = i >> 3, f4 = i & 7;
      *(float4*)(&zc[row][f4 * 4]) = *(const float4*)(zrow + row * EMB_DIM + dc * 32 + f4 * 4);
    }
    __syncthreads();
    const int half = dc >> 2;
    #pragma unroll
    for (int q = 0; q < 4; ++q)
      #pragma unroll
      for (int jj = 0; jj < 2; ++jj) {
        float v = zc[prow][(pm * 2 + jj) + 8 * q];
        racc[half][jj] = __fadd_rn(racc[half][jj], __fmul_rn(v, v));
      }
  }
  pmm[prow][0][pm] = __fadd_rn(racc[0][0], racc[0][1]);
  pmm[prow][1][pm] = __fadd_rn(racc[1][0], racc[1][1]);
  __syncthreads();
  if (tid < 64) {
    float h0 = __fadd_rn(__fadd_rn(pmm[tid][0][0], pmm[tid][0][1]),
                         __fadd_rn(pmm[tid][0][2], pmm[tid][0][3]));
    float h1 = __fadd_rn(__fadd_rn(pmm[tid][1][0], pmm[tid][1][1]),
                         __fadd_rn(pmm[tid][1][2], pmm[tid][1][3]));
    r2out[n0 + tid] = __fadd_rn(h0, h1);
  }
}

// bf16 MFMA approx-distance sweep + candidate capture.
// 256 rows x 1024 codes per block, 1024 threads (16 waves), grid=256 (1 block/CU).
// Round-5 fixes (semantics identical to round 4):
//  - Bl unit XOR-swizzle (unit = code*4 + (seg^((code>>1)&3))): B-reads were
//    8-way bank conflicts (bank = (code&1)*16+quad*4); now 2-way both sides.
//  - lgkm-only barriers in the whole kernel: no vmcnt(0) drain at barriers, so
//    the bpre register prefetch rides across; LDS ordering fully preserved.
//  - ballot-aggregated llist append: 1 LDS atomic per wave-group, not per cand.
__global__ __launch_bounds__(MTHREADS) void vq_mfma(
    const float* __restrict__ z, const unsigned short* __restrict__ embTbf,
    const float* __restrict__ cvec, unsigned long long* __restrict__ slots,
    int* __restrict__ gcnt, unsigned int* __restrict__ glist,
    int* __restrict__ grm) {
  __shared__ unsigned short zc[256][256];   // 131072 B, 16B-unit XOR swizzle
  __shared__ unsigned short Bl[2][8192];    // 2 x 16384 B flat double buffer

  // capture-scratch overlay on Bl[1] (16384 B = 4096 ints):
  //   [0..255] rowminb, [256] lcnt, [257] lbase, [258] lcount, [259..4095] llist
  int* caps = (int*)&Bl[1][0];
  unsigned int* llist = (unsigned int*)caps + 259;   // LLCAP = 4096-259 = 3837

  const int tid = threadIdx.x;
  const int lane = tid & 63, wave = tid >> 6;
  const int quad = lane >> 4, l15 = lane & 15;
  const int rg = wave >> 2, cg = wave & 3;   // 4 row-groups x 4 code-groups
  const int n0 = blockIdx.x * 256;

  if (tid < 256) {
    grm[n0 + tid] = 0x7F000000;              // block-private rows; same-thread order
    slots[n0 + tid] = ~0ULL;
  }

  // stage A: 256 rows z fp32 -> bf16 swizzled LDS (coalesced, conflict-free)
  #pragma unroll
  for (int it = 0; it < 8; ++it) {
    int g = tid + it * MTHREADS, row = g >> 5, u = g & 31;
    const float* src = z + (size_t)(n0 + row) * EMB_DIM + u * 8;
    float4 a = *(const float4*)src;
    float4 b = *(const float4*)(src + 4);
    uint4 w;
    w.x = ((unsigned)f2bf(a.y) << 16) | f2bf(a.x);
    w.y = ((unsigned)f2bf(a.w) << 16) | f2bf(a.z);
    w.z = ((unsigned)f2bf(b.y) << 16) | f2bf(b.x);
    w.w = ((unsigned)f2bf(b.w) << 16) | f2bf(b.z);
    *(uint4*)(&zc[row][(u ^ (row & 7)) * 8]) = w;
  }

  // B staging geometry: thread tid -> (code bn, seg bseg); swizzled 16B unit.
  const int bn = tid >> 2, bseg = tid & 3;
  const size_t bofs = (size_t)bn * EMB_DIM + (size_t)bseg * 8;
  const int bunit = bn * 4 + (bseg ^ ((bn >> 1) & 3));       // LDS write unit
  // LDS read units (code local to tile; constant across j and kc)
  int bidx[4];
  #pragma unroll
  for (int ct = 0; ct < 4; ++ct) {
    int cn = cg * 64 + ct * 16 + l15;
    bidx[ct] = (cn * 4 + (quad ^ ((cn >> 1) & 3))) * 8;
  }

  uint4 p0 = *(const uint4*)(embTbf + bofs);                 // chunk 0
  BAR_LGKM();                                 // A (zc) ready
  *(uint4*)(&Bl[0][(size_t)bunit * 8]) = p0;                 // write chunk 0 (even)
  uint4 bpre = *(const uint4*)(embTbf + 32 + bofs);          // chunk 1
  BAR_LGKM();                                 // chunk 0 visible

  for (int j = 0; j < 4; ++j) {               // 4 j-tiles x 256 codes
    f32x4 acc[4][4];
    #pragma unroll
    for (int rt = 0; rt < 4; ++rt)
      #pragma unroll
      for (int ct = 0; ct < 4; ++ct)
        acc[rt][ct] = (f32x4){0.f, 0.f, 0.f, 0.f};
    float c2r[4];
    #pragma unroll
    for (int ct = 0; ct < 4; ++ct)
      c2r[ct] = cvec[j * 256 + cg * 64 + ct * 16 + l15] + 1.0f;

    for (int kc = 0; kc < 8; ++kc) {
      const int c = j * 8 + kc;               // current chunk, lives in Bl[c&1]
      if (c < 31)                              // write next chunk (c+1)
        *(uint4*)(&Bl[(c + 1) & 1][(size_t)bunit * 8]) = bpre;
      if (c + 2 < 32)                          // issue load of chunk c+2
        bpre = *(const uint4*)(embTbf + (size_t)((c + 2) >> 3) * 65536 +
                               (size_t)((c + 2) & 7) * 32 + bofs);
      bf16x8 av[4], bv[4];
      #pragma unroll
      for (int rt = 0; rt < 4; ++rt) {
        int row = rg * 64 + rt * 16 + l15;
        av[rt] = *(const bf16x8*)(&zc[row][((kc * 4 + quad) ^ (l15 & 7)) * 8]);
      }
      #pragma unroll
      for (int ct = 0; ct < 4; ++ct)
        bv[ct] = *(const bf16x8*)(&Bl[c & 1][(size_t)bidx[ct]]);
      #pragma unroll
      for (int rt = 0; rt < 4; ++rt)
        #pragma unroll
        for (int ct = 0; ct < 4; ++ct)
          acc[rt][ct] = __builtin_amdgcn_mfma_f32_16x16x32_bf16(av[rt], bv[ct], acc[rt][ct], 0, 0, 0);
      BAR_LGKM();                              // single lgkm barrier per chunk
    }
    // ---- capture phase: Bl[1] free (chunk 8j+7 consumed; next write after last barrier)
    if (tid < 256) caps[tid] = 0x7F000000;     // rowminb init
    if (tid == 0) caps[256] = 0;               // lcnt
    BAR_LGKM();

    // per-wave 64-code row-min -> LDS atomicMin (tight, block-wide)
    #pragma unroll
    for (int rt = 0; rt < 4; ++rt)
      #pragma unroll
      for (int reg = 0; reg < 4; ++reg) {
        float m = 1e30f;
        #pragma unroll
        for (int ct = 0; ct < 4; ++ct) {
          float d = fmaf(-2.f, acc[rt][ct][reg], c2r[ct]);
          m = fminf(m, d);
        }
        #pragma unroll
        for (int off = 1; off < 16; off <<= 1)
          m = fminf(m, __shfl_xor(m, off));
        if (l15 == 0)
          atomicMin(&caps[rg * 64 + rt * 16 + quad * 4 + reg], __float_as_int(m));
      }
    BAR_LGKM();                                // rowminb final for this j

    // merge with global running min across j (returning atomicMin)
    if (tid < 256) {
      int lm = caps[tid];
      int old = atomicMin(&grm[n0 + tid], lm);
      caps[tid] = lm < old ? lm : old;
    }
    BAR_LGKM();                                // merged bound visible

    // capture candidates within EPSF of running min -> LDS llist
    // (ballot-aggregated: one LDS atomic per wave per hit-group)
    #pragma unroll
    for (int rt = 0; rt < 4; ++rt)
      #pragma unroll
      for (int reg = 0; reg < 4; ++reg) {
        int rowl = rg * 64 + rt * 16 + quad * 4 + reg;
        float fmin = __int_as_float(caps[rowl]);
        #pragma unroll
        for (int ct = 0; ct < 4; ++ct) {
          float d = fmaf(-2.f, acc[rt][ct][reg], c2r[ct]);
          bool pred = (d <= fmin + EPSF);
          unsigned long long msk = __ballot(pred);
          if (msk) {
            int leader = (int)(__ffsll((long long)msk) - 1);
            int cnt = (int)__popcll(msk);
            int base0 = 0;
            if (lane == leader) base0 = atomicAdd(&caps[256], cnt);
            base0 = __shfl(base0, leader);
            if (pred) {
              int id = base0 + (int)__popcll(msk & ((1ULL << lane) - 1ULL));
              int k = j * 256 + cg * 64 + ct * 16 + l15;
              if (id < LLCAP)
                llist[id] = ((unsigned)(n0 + rowl) << 10) | (unsigned)k;
            }
          }
        }
      }
    BAR_LGKM();
    if (tid == 0) {
      int c = caps[256]; if (c > LLCAP) c = LLCAP;
      caps[258] = c;
      caps[257] = atomicAdd(gcnt, c);          // ONE global atomic per block per j
    }
    BAR_LGKM();
    {
      int cnt = caps[258], base = caps[257];
      for (int i = tid; i < cnt; i += MTHREADS)
        if (base + i < GCAP) glist[base + i] = llist[i];
    }
    BAR_LGKM();                                // Bl[1] safe to rewrite next j
  }
}

// exact numpy-fp32 re-evaluation of captured pairs [arithmetic verified round 3]
__global__ __launch_bounds__(NTHREADS) void vq_refine(
    const float* __restrict__ z, const float* __restrict__ embTf,
    const float* __restrict__ r2, const float* __restrict__ cvec,
    const int* __restrict__ gcnt, const unsigned int* __restrict__ glist,
    unsigned long long* __restrict__ slots) {
  int n = *gcnt; if (n > GCAP) n = GCAP;
  for (int i = blockIdx.x * NTHREADS + threadIdx.x; i < n;
       i += gridDim.x * NTHREADS) {
    unsigned e = glist[i];
    int grow = (int)(e >> 10), k = (int)(e & 1023);
    const float* zr = z + (size_t)grow * EMB_DIM;
    const float* er = embTf + (size_t)k * EMB_DIM;
    float s = 0.f;
    for (int d = 0; d < EMB_DIM; ++d)       // strict sequential-d fmaf chain
      s = fmaf(zr[d], er[d], s);
    float dist = __fsub_rn(__fadd_rn(r2[grow], cvec[k]), __fmul_rn(2.0f, s));
    unsigned long long key =
        ((unsigned long long)__float_as_uint(dist) << 32) | (unsigned)k;
    atomicMin(&slots[grow], key);
  }
}

// final index + gather + straight-through write + loss + histogram
__global__ __launch_bounds__(NTHREADS) void vq_epi(
    const float* __restrict__ z, const float* __restrict__ embTf,
    const unsigned long long* __restrict__ slots,
    float* __restrict__ out, int* __restrict__ hist, float* __restrict__ loss) {
  __shared__ int ks[64];
  __shared__ float wsum[4];
  const int tid = threadIdx.x;
  const int n0 = blockIdx.x * 64;
  const float* zrow = z + (size_t)n0 * EMB_DIM;
  if (tid < 64) {
    int k = (int)(slots[n0 + tid] & 1023ULL);
    ks[tid] = k;
    out[OFF_IDX + n0 + tid] = (float)k;
    atomicAdd(&hist[k], 1);
  }
  __syncthreads();
  float sumsq = 0.f;
  #pragma unroll
  for (int it = 0; it < 16; ++it) {
    int g = tid + it * NTHREADS;
    int row = g >> 6;
    int d = (g & 63) * 4;
    int k = ks[row];
    float4 zv = *(const float4*)(zrow + row * EMB_DIM + d);
    float4 q = *(const float4*)(embTf + (size_t)k * EMB_DIM + d);
    float4 df;
    df.x = q.x - zv.x; df.y = q.y - zv.y; df.z = q.z - zv.z; df.w = q.w - zv.w;
    sumsq = fmaf(df.x, df.x, sumsq);
    sumsq = fmaf(df.y, df.y, sumsq);
    sumsq = fmaf(df.z, df.z, sumsq);
    sumsq = fmaf(df.w, df.w, sumsq);
    *(float4*)(out + (size_t)(n0 + row) * EMB_DIM + d) = q;
  }
  #pragma unroll
  for (int off = 32; off > 0; off >>= 1) sumsq += __shfl_down(sumsq, off);
  if ((tid & 63) == 0) wsum[tid >> 6] = sumsq;
  __syncthreads();
  if (tid == 0) atomicAdd(loss, wsum[0] + wsum[1] + wsum[2] + wsum[3]);
}

__global__ __launch_bounds__(NTHREADS) void vq_finalize(
    const int* __restrict__ hist, const float* __restrict__ loss,
    float* __restrict__ out) {
  __shared__ float ws[4];
  int tid = threadIdx.x;
  float s = 0.f;
  for (int k = tid; k < NUM_EMB; k += NTHREADS) {
    float p = (float)hist[k] * (1.0f / 65536.0f);
    s += p * logf(p + 1e-10f);
  }
  #pragma unroll
  for (int off = 32; off > 0; off >>= 1) s += __shfl_down(s, off);
  if ((tid & 63) == 0) ws[tid >> 6] = s;
  __syncthreads();
  if (tid == 0) {
    float tot = ws[0] + ws[1] + ws[2] + ws[3];
    float vq = *loss * (1.0f / 16777216.0f);
    out[OFF_VQ + 0] = vq;
    out[OFF_VQ + 1] = 0.25f * vq;
    out[OFF_VQ + 2] = expf(-tot);
  }
}

extern "C" void kernel_launch(void* const* d_in, const int* in_sizes, int n_in,
                              void* d_out, int out_size, void* d_ws, size_t ws_size,
                              hipStream_t stream) {
  const float* z   = (const float*)d_in[0];
  const float* emb = (const float*)d_in[1];
  float* out = (float*)d_out;
  char* ws = (char*)d_ws;
  float* cvec   = (float*)(ws + WS_C2);
  int*   hist   = (int*)(ws + WS_HIST);
  float* loss   = (float*)(ws + WS_LOSS);
  int*   gcnt   = (int*)(ws + WS_GCNT);
  float* r2     = (float*)(ws + WS_R2);
  unsigned long long* slots = (unsigned long long*)(ws + WS_SLOT);
  float* embTf  = (float*)(ws + WS_ETF);
  unsigned short* embTbf = (unsigned short*)(ws + WS_ETB);
  int*   grm    = (int*)(ws + WS_RMIN);
  unsigned int* glist = (unsigned int*)(ws + WS_GLIST);

  vq_pt<<<68, NTHREADS, 0, stream>>>(emb, cvec, hist, loss, gcnt, embTf, embTbf);
  vq_r2k<<<NROWS / 64, NTHREADS, 0, stream>>>(z, r2);
  vq_mfma<<<NROWS / 256, MTHREADS, 0, stream>>>(z, embTbf, cvec, slots, gcnt, glist, grm);
  vq_refine<<<512, NTHREADS, 0, stream>>>(z, embTf, r2, cvec, gcnt, glist, slots);
  vq_epi<<<NROWS / 64, NTHREADS, 0, stream>>>(z, embTf, slots, out, hist, loss);
  vq_finalize<<<1, NTHREADS, 0, stream>>>(hist, loss, out);
}

// Round 6
// 289.175 us; speedup vs baseline: 1.0029x; 1.0029x over previous
//
#include <hip/hip_runtime.h>
#include <math.h>

#define NUM_EMB 1024
#define EMB_DIM 256
#define NROWS   65536
#define NTHREADS 256
#define MTHREADS 1024
#define EPSF 1.5e-3f
#define GCAP 458752
#define LLCAP 3837

// out layout (float32, concatenated):
#define OFF_IDX  16777216
#define OFF_VQ   16842752

// ws layout (bytes):
#define WS_C2    0         // float[1024]  ||e_k||^2 sequential fp32 (verified)
#define WS_HIST  4096      // int[1024]
#define WS_LOSS  8192      // float
#define WS_GCNT  8196      // int
#define WS_R2    8448      // float[65536] numpy-pairwise ||z_n||^2 (verified)
#define WS_SLOT  270592    // ull[65536]  packed (dist_bits<<32)|k
#define WS_ETF   794880    // float[1024][256]  emb^T fp32
#define WS_ETB   1843456   // ushort[1024][256] emb^T bf16
#define WS_RMIN  2367744   // int[65536]  bf16 running row-min bits (block-private rows)
#define WS_GLIST 2629888   // uint[GCAP] packed (row<<10)|k

typedef __attribute__((ext_vector_type(8))) short bf16x8;
typedef __attribute__((ext_vector_type(4))) float f32x4;

// lgkm-only barrier: orders all LDS ops across the block WITHOUT draining the
// global-load queue (vmcnt), so register prefetches ride across. Memory
// clobbers fence compiler reordering on both sides (rule 18).
#define BAR_LGKM() do {                                        \
    asm volatile("s_waitcnt lgkmcnt(0)" ::: "memory");         \
    __builtin_amdgcn_s_barrier();                              \
    asm volatile("" ::: "memory");                             \
  } while (0)

__device__ __forceinline__ unsigned short f2bf(float x) {
  unsigned u = __float_as_uint(x);
  unsigned r = (u + 0x7FFFu + ((u >> 16) & 1u)) >> 16;
  return (unsigned short)r;
}

// merged: c2 prep (blocks 0..3) + transpose (blocks 4..67)
__global__ __launch_bounds__(NTHREADS) void vq_pt(
    const float* __restrict__ emb, float* __restrict__ cvec,
    int* __restrict__ hist, float* __restrict__ loss, int* __restrict__ gcnt,
    float* __restrict__ embTf, unsigned short* __restrict__ embTbf) {
  __shared__ float t[64][65];
  const int tid = threadIdx.x;
  if (blockIdx.x < 4) {
    // c2[k] = sequential fp32 sum of fl(e[d,k]^2)  [verified round 3]
    int k = blockIdx.x * NTHREADS + tid;
    float s = 0.f;
    for (int d = 0; d < EMB_DIM; ++d) {
      float v = emb[d * NUM_EMB + k];
      s = __fadd_rn(s, __fmul_rn(v, v));
    }
    cvec[k] = s;
    hist[k] = 0;
    if (k == 0) { *loss = 0.f; *gcnt = 0; }
  } else {
    // transpose emb [256][1024] -> embTf fp32 [1024][256] + embTbf bf16
    const int b = blockIdx.x - 4;
    const int kt = b & 15, dt = b >> 4;
    #pragma unroll
    for (int it = 0; it < 16; ++it) {
      int i = tid + it * NTHREADS, r = i >> 6, c = i & 63;
      t[r][c] = emb[(dt * 64 + r) * NUM_EMB + kt * 64 + c];
    }
    __syncthreads();
    #pragma unroll
    for (int it = 0; it < 16; ++it) {
      int i = tid + it * NTHREADS, r = i >> 6, c = i & 63;
      float v = t[c][r];
      embTf[(kt * 64 + r) * EMB_DIM + dt * 64 + c] = v;
      embTbf[(kt * 64 + r) * EMB_DIM + dt * 64 + c] = f2bf(v);
    }
  }
}

// r2[n] = numpy pairwise fp32 sum of z[n,:]**2  [verified round 3, verbatim]
__global__ __launch_bounds__(NTHREADS) void vq_r2k(
    const float* __restrict__ z, float* __restrict__ r2out) {
  __shared__ float zc[64][36];
  __shared__ float pmm[64][2][4];
  const int tid = threadIdx.x;
  const int n0 = blockIdx.x * 64;
  const float* zrow = z + (size_t)n0 * EMB_DIM;
  const int prow = tid >> 2, pm = tid & 3;
  float racc[2][2] = {{0.f, 0.f}, {0.f, 0.f}};
  for (int dc = 0; dc < 8; ++dc) {
    __syncthreads();
    #pragma unroll
    for (int it = 0; it < 2; ++it) {
      int i = tid + it * NTHREADS, row = i >> 3, f4 = i & 7;
      *(float4*)(&zc[row][f4 * 4]) = *(const float4*)(zrow + row * EMB_DIM + dc * 32 + f4 * 4);
    }
    __syncthreads();
    const int half = dc >> 2;
    #pragma unroll
    for (int q = 0; q < 4; ++q)
      #pragma unroll
      for (int jj = 0; jj < 2; ++jj) {
        float v = zc[prow][(pm * 2 + jj) + 8 * q];
        racc[half][jj] = __fadd_rn(racc[half][jj], __fmul_rn(v, v));
      }
  }
  pmm[prow][0][pm] = __fadd_rn(racc[0][0], racc[0][1]);
  pmm[prow][1][pm] = __fadd_rn(racc[1][0], racc[1][1]);
  __syncthreads();
  if (tid < 64) {
    float h0 = __fadd_rn(__fadd_rn(pmm[tid][0][0], pmm[tid][0][1]),
                         __fadd_rn(pmm[tid][0][2], pmm[tid][0][3]));
    float h1 = __fadd_rn(__fadd_rn(pmm[tid][1][0], pmm[tid][1][1]),
                         __fadd_rn(pmm[tid][1][2], pmm[tid][1][3]));
    r2out[n0 + tid] = __fadd_rn(h0, h1);
  }
}

// bf16 MFMA approx-distance sweep + candidate capture.
// 256 rows x 1024 codes per block, 1024 threads (16 waves), grid=256 (1 block/CU).
// Round-6 change (ONLY one): __launch_bounds__(1024, 4).
//   Evidence: rounds 1/4/5 all pinned at ~85us with VGPR_Count=64 and
//   WRITE_SIZE 22-30MB (vs 1.4MB at 256-thread blocks) -> scratch spill
//   traffic. Without the min-waves arg the compiler budgeted 128 unified
//   regs/wave (64 arch + 64 acc), below the ~150+ live set (acc 64 +
//   av/bv 64 + addresses), spilling in the kc loop. LDS (160KiB) already
//   hard-caps at 1 block/CU = 4 waves/EU, so declare exactly that and let
//   the allocator use ~512 unified regs/wave. Everything else identical
//   to round 5 (clean A/B on the spill theory).
__global__ __launch_bounds__(MTHREADS, 4) void vq_mfma(
    const float* __restrict__ z, const unsigned short* __restrict__ embTbf,
    const float* __restrict__ cvec, unsigned long long* __restrict__ slots,
    int* __restrict__ gcnt, unsigned int* __restrict__ glist,
    int* __restrict__ grm) {
  __shared__ unsigned short zc[256][256];   // 131072 B, 16B-unit XOR swizzle
  __shared__ unsigned short Bl[2][8192];    // 2 x 16384 B flat double buffer

  // capture-scratch overlay on Bl[1] (16384 B = 4096 ints):
  //   [0..255] rowminb, [256] lcnt, [257] lbase, [258] lcount, [259..4095] llist
  int* caps = (int*)&Bl[1][0];
  unsigned int* llist = (unsigned int*)caps + 259;   // LLCAP = 4096-259 = 3837

  const int tid = threadIdx.x;
  const int lane = tid & 63, wave = tid >> 6;
  const int quad = lane >> 4, l15 = lane & 15;
  const int rg = wave >> 2, cg = wave & 3;   // 4 row-groups x 4 code-groups
  const int n0 = blockIdx.x * 256;

  if (tid < 256) {
    grm[n0 + tid] = 0x7F000000;              // block-private rows; same-thread order
    slots[n0 + tid] = ~0ULL;
  }

  // stage A: 256 rows z fp32 -> bf16 swizzled LDS (coalesced, conflict-free)
  #pragma unroll
  for (int it = 0; it < 8; ++it) {
    int g = tid + it * MTHREADS, row = g >> 5, u = g & 31;
    const float* src = z + (size_t)(n0 + row) * EMB_DIM + u * 8;
    float4 a = *(const float4*)src;
    float4 b = *(const float4*)(src + 4);
    uint4 w;
    w.x = ((unsigned)f2bf(a.y) << 16) | f2bf(a.x);
    w.y = ((unsigned)f2bf(a.w) << 16) | f2bf(a.z);
    w.z = ((unsigned)f2bf(b.y) << 16) | f2bf(b.x);
    w.w = ((unsigned)f2bf(b.w) << 16) | f2bf(b.z);
    *(uint4*)(&zc[row][(u ^ (row & 7)) * 8]) = w;
  }

  // B staging geometry: thread tid -> (code bn, seg bseg); swizzled 16B unit.
  const int bn = tid >> 2, bseg = tid & 3;
  const size_t bofs = (size_t)bn * EMB_DIM + (size_t)bseg * 8;
  const int bunit = bn * 4 + (bseg ^ ((bn >> 1) & 3));       // LDS write unit
  // LDS read units (code local to tile; constant across j and kc)
  int bidx[4];
  #pragma unroll
  for (int ct = 0; ct < 4; ++ct) {
    int cn = cg * 64 + ct * 16 + l15;
    bidx[ct] = (cn * 4 + (quad ^ ((cn >> 1) & 3))) * 8;
  }

  uint4 p0 = *(const uint4*)(embTbf + bofs);                 // chunk 0
  BAR_LGKM();                                 // A (zc) ready
  *(uint4*)(&Bl[0][(size_t)bunit * 8]) = p0;                 // write chunk 0 (even)
  uint4 bpre = *(const uint4*)(embTbf + 32 + bofs);          // chunk 1
  BAR_LGKM();                                 // chunk 0 visible

  for (int j = 0; j < 4; ++j) {               // 4 j-tiles x 256 codes
    f32x4 acc[4][4];
    #pragma unroll
    for (int rt = 0; rt < 4; ++rt)
      #pragma unroll
      for (int ct = 0; ct < 4; ++ct)
        acc[rt][ct] = (f32x4){0.f, 0.f, 0.f, 0.f};
    float c2r[4];
    #pragma unroll
    for (int ct = 0; ct < 4; ++ct)
      c2r[ct] = cvec[j * 256 + cg * 64 + ct * 16 + l15] + 1.0f;

    for (int kc = 0; kc < 8; ++kc) {
      const int c = j * 8 + kc;               // current chunk, lives in Bl[c&1]
      if (c < 31)                              // write next chunk (c+1)
        *(uint4*)(&Bl[(c + 1) & 1][(size_t)bunit * 8]) = bpre;
      if (c + 2 < 32)                          // issue load of chunk c+2
        bpre = *(const uint4*)(embTbf + (size_t)((c + 2) >> 3) * 65536 +
                               (size_t)((c + 2) & 7) * 32 + bofs);
      bf16x8 av[4], bv[4];
      #pragma unroll
      for (int rt = 0; rt < 4; ++rt) {
        int row = rg * 64 + rt * 16 + l15;
        av[rt] = *(const bf16x8*)(&zc[row][((kc * 4 + quad) ^ (l15 & 7)) * 8]);
      }
      #pragma unroll
      for (int ct = 0; ct < 4; ++ct)
        bv[ct] = *(const bf16x8*)(&Bl[c & 1][(size_t)bidx[ct]]);
      #pragma unroll
      for (int rt = 0; rt < 4; ++rt)
        #pragma unroll
        for (int ct = 0; ct < 4; ++ct)
          acc[rt][ct] = __builtin_amdgcn_mfma_f32_16x16x32_bf16(av[rt], bv[ct], acc[rt][ct], 0, 0, 0);
      BAR_LGKM();                              // single lgkm barrier per chunk
    }
    // ---- capture phase: Bl[1] free (chunk 8j+7 consumed; next write after last barrier)
    if (tid < 256) caps[tid] = 0x7F000000;     // rowminb init
    if (tid == 0) caps[256] = 0;               // lcnt
    BAR_LGKM();

    // per-wave 64-code row-min -> LDS atomicMin (tight, block-wide)
    #pragma unroll
    for (int rt = 0; rt < 4; ++rt)
      #pragma unroll
      for (int reg = 0; reg < 4; ++reg) {
        float m = 1e30f;
        #pragma unroll
        for (int ct = 0; ct < 4; ++ct) {
          float d = fmaf(-2.f, acc[rt][ct][reg], c2r[ct]);
          m = fminf(m, d);
        }
        #pragma unroll
        for (int off = 1; off < 16; off <<= 1)
          m = fminf(m, __shfl_xor(m, off));
        if (l15 == 0)
          atomicMin(&caps[rg * 64 + rt * 16 + quad * 4 + reg], __float_as_int(m));
      }
    BAR_LGKM();                                // rowminb final for this j

    // merge with global running min across j (returning atomicMin)
    if (tid < 256) {
      int lm = caps[tid];
      int old = atomicMin(&grm[n0 + tid], lm);
      caps[tid] = lm < old ? lm : old;
    }
    BAR_LGKM();                                // merged bound visible

    // capture candidates within EPSF of running min -> LDS llist
    // (ballot-aggregated: one LDS atomic per wave per hit-group)
    #pragma unroll
    for (int rt = 0; rt < 4; ++rt)
      #pragma unroll
      for (int reg = 0; reg < 4; ++reg) {
        int rowl = rg * 64 + rt * 16 + quad * 4 + reg;
        float fmin = __int_as_float(caps[rowl]);
        #pragma unroll
        for (int ct = 0; ct < 4; ++ct) {
          float d = fmaf(-2.f, acc[rt][ct][reg], c2r[ct]);
          bool pred = (d <= fmin + EPSF);
          unsigned long long msk = __ballot(pred);
          if (msk) {
            int leader = (int)(__ffsll((long long)msk) - 1);
            int cnt = (int)__popcll(msk);
            int base0 = 0;
            if (lane == leader) base0 = atomicAdd(&caps[256], cnt);
            base0 = __shfl(base0, leader);
            if (pred) {
              int id = base0 + (int)__popcll(msk & ((1ULL << lane) - 1ULL));
              int k = j * 256 + cg * 64 + ct * 16 + l15;
              if (id < LLCAP)
                llist[id] = ((unsigned)(n0 + rowl) << 10) | (unsigned)k;
            }
          }
        }
      }
    BAR_LGKM();
    if (tid == 0) {
      int c = caps[256]; if (c > LLCAP) c = LLCAP;
      caps[258] = c;
      caps[257] = atomicAdd(gcnt, c);          // ONE global atomic per block per j
    }
    BAR_LGKM();
    {
      int cnt = caps[258], base = caps[257];
      for (int i = tid; i < cnt; i += MTHREADS)
        if (base + i < GCAP) glist[base + i] = llist[i];
    }
    BAR_LGKM();                                // Bl[1] safe to rewrite next j
  }
}

// exact numpy-fp32 re-evaluation of captured pairs [arithmetic verified round 3]
__global__ __launch_bounds__(NTHREADS) void vq_refine(
    const float* __restrict__ z, const float* __restrict__ embTf,
    const float* __restrict__ r2, const float* __restrict__ cvec,
    const int* __restrict__ gcnt, const unsigned int* __restrict__ glist,
    unsigned long long* __restrict__ slots) {
  int n = *gcnt; if (n > GCAP) n = GCAP;
  for (int i = blockIdx.x * NTHREADS + threadIdx.x; i < n;
       i += gridDim.x * NTHREADS) {
    unsigned e = glist[i];
    int grow = (int)(e >> 10), k = (int)(e & 1023);
    const float* zr = z + (size_t)grow * EMB_DIM;
    const float* er = embTf + (size_t)k * EMB_DIM;
    float s = 0.f;
    for (int d = 0; d < EMB_DIM; ++d)       // strict sequential-d fmaf chain
      s = fmaf(zr[d], er[d], s);
    float dist = __fsub_rn(__fadd_rn(r2[grow], cvec[k]), __fmul_rn(2.0f, s));
    unsigned long long key =
        ((unsigned long long)__float_as_uint(dist) << 32) | (unsigned)k;
    atomicMin(&slots[grow], key);
  }
}

// final index + gather + straight-through write + loss + histogram
__global__ __launch_bounds__(NTHREADS) void vq_epi(
    const float* __restrict__ z, const float* __restrict__ embTf,
    const unsigned long long* __restrict__ slots,
    float* __restrict__ out, int* __restrict__ hist, float* __restrict__ loss) {
  __shared__ int ks[64];
  __shared__ float wsum[4];
  const int tid = threadIdx.x;
  const int n0 = blockIdx.x * 64;
  const float* zrow = z + (size_t)n0 * EMB_DIM;
  if (tid < 64) {
    int k = (int)(slots[n0 + tid] & 1023ULL);
    ks[tid] = k;
    out[OFF_IDX + n0 + tid] = (float)k;
    atomicAdd(&hist[k], 1);
  }
  __syncthreads();
  float sumsq = 0.f;
  #pragma unroll
  for (int it = 0; it < 16; ++it) {
    int g = tid + it * NTHREADS;
    int row = g >> 6;
    int d = (g & 63) * 4;
    int k = ks[row];
    float4 zv = *(const float4*)(zrow + row * EMB_DIM + d);
    float4 q = *(const float4*)(embTf + (size_t)k * EMB_DIM + d);
    float4 df;
    df.x = q.x - zv.x; df.y = q.y - zv.y; df.z = q.z - zv.z; df.w = q.w - zv.w;
    sumsq = fmaf(df.x, df.x, sumsq);
    sumsq = fmaf(df.y, df.y, sumsq);
    sumsq = fmaf(df.z, df.z, sumsq);
    sumsq = fmaf(df.w, df.w, sumsq);
    *(float4*)(out + (size_t)(n0 + row) * EMB_DIM + d) = q;
  }
  #pragma unroll
  for (int off = 32; off > 0; off >>= 1) sumsq += __shfl_down(sumsq, off);
  if ((tid & 63) == 0) wsum[tid >> 6] = sumsq;
  __syncthreads();
  if (tid == 0) atomicAdd(loss, wsum[0] + wsum[1] + wsum[2] + wsum[3]);
}

__global__ __launch_bounds__(NTHREADS) void vq_finalize(
    const int* __restrict__ hist, const float* __restrict__ loss,
    float* __restrict__ out) {
  __shared__ float ws[4];
  int tid = threadIdx.x;
  float s = 0.f;
  for (int k = tid; k < NUM_EMB; k += NTHREADS) {
    float p = (float)hist[k] * (1.0f / 65536.0f);
    s += p * logf(p + 1e-10f);
  }
  #pragma unroll
  for (int off = 32; off > 0; off >>= 1) s += __shfl_down(s, off);
  if ((tid & 63) == 0) ws[tid >> 6] = s;
  __syncthreads();
  if (tid == 0) {
    float tot = ws[0] + ws[1] + ws[2] + ws[3];
    float vq = *loss * (1.0f / 16777216.0f);
    out[OFF_VQ + 0] = vq;
    out[OFF_VQ + 1] = 0.25f * vq;
    out[OFF_VQ + 2] = expf(-tot);
  }
}

extern "C" void kernel_launch(void* const* d_in, const int* in_sizes, int n_in,
                              void* d_out, int out_size, void* d_ws, size_t ws_size,
                              hipStream_t stream) {
  const float* z   = (const float*)d_in[0];
  const float* emb = (const float*)d_in[1];
  float* out = (float*)d_out;
  char* ws = (char*)d_ws;
  float* cvec   = (float*)(ws + WS_C2);
  int*   hist   = (int*)(ws + WS_HIST);
  float* loss   = (float*)(ws + WS_LOSS);
  int*   gcnt   = (int*)(ws + WS_GCNT);
  float* r2     = (float*)(ws + WS_R2);
  unsigned long long* slots = (unsigned long long*)(ws + WS_SLOT);
  float* embTf  = (float*)(ws + WS_ETF);
  unsigned short* embTbf = (unsigned short*)(ws + WS_ETB);
  int*   grm    = (int*)(ws + WS_RMIN);
  unsigned int* glist = (unsigned int*)(ws + WS_GLIST);

  vq_pt<<<68, NTHREADS, 0, stream>>>(emb, cvec, hist, loss, gcnt, embTf, embTbf);
  vq_r2k<<<NROWS / 64, NTHREADS, 0, stream>>>(z, r2);
  vq_mfma<<<NROWS / 256, MTHREADS, 0, stream>>>(z, embTbf, cvec, slots, gcnt, glist, grm);
  vq_refine<<<512, NTHREADS, 0, stream>>>(z, embTf, r2, cvec, gcnt, glist, slots);
  vq_epi<<<NROWS / 64, NTHREADS, 0, stream>>>(z, embTf, slots, out, hist, loss);
  vq_finalize<<<1, NTHREADS, 0, stream>>>(hist, loss, out);
}

// Round 7
// 283.324 us; speedup vs baseline: 1.0236x; 1.0207x over previous
//
#include <hip/hip_runtime.h>
#include <math.h>

#define NUM_EMB 1024
#define EMB_DIM 256
#define NROWS   65536
#define NTHREADS 256
#define MTHREADS 512
#define MROWS   128
#define EPSF 1.5e-3f
#define GCAP 458752
#define LLCAP 3965

// out layout (float32, concatenated):
#define OFF_IDX  16777216
#define OFF_VQ   16842752

// ws layout (bytes):
#define WS_C2    0         // float[1024]  ||e_k||^2 sequential fp32 (verified)
#define WS_HIST  4096      // int[1024]
#define WS_LOSS  8192      // float
#define WS_GCNT  8196      // int
#define WS_R2    8448      // float[65536] numpy-pairwise ||z_n||^2 (verified)
#define WS_SLOT  270592    // ull[65536]  packed (dist_bits<<32)|k
#define WS_ETF   794880    // float[1024][256]  emb^T fp32
#define WS_ETB   1843456   // ushort[1024][256] emb^T bf16
#define WS_RMIN  2367744   // int[65536]  bf16 running row-min bits (block-private rows)
#define WS_GLIST 2629888   // uint[GCAP] packed (row<<10)|k

typedef __attribute__((ext_vector_type(8))) short bf16x8;
typedef __attribute__((ext_vector_type(4))) float f32x4;

// lgkm-only barrier: orders all LDS ops across the block WITHOUT draining the
// global-load queue (vmcnt), so register prefetches ride across. Memory
// clobbers fence compiler reordering on both sides (rule 18).
#define BAR_LGKM() do {                                        \
    asm volatile("s_waitcnt lgkmcnt(0)" ::: "memory");         \
    __builtin_amdgcn_s_barrier();                              \
    asm volatile("" ::: "memory");                             \
  } while (0)

__device__ __forceinline__ unsigned short f2bf(float x) {
  unsigned u = __float_as_uint(x);
  unsigned r = (u + 0x7FFFu + ((u >> 16) & 1u)) >> 16;
  return (unsigned short)r;
}

// merged: c2 prep (blocks 0..3) + transpose (blocks 4..67) + r2 (blocks 68..1091)
__global__ __launch_bounds__(NTHREADS) void vq_pt(
    const float* __restrict__ emb, float* __restrict__ cvec,
    int* __restrict__ hist, float* __restrict__ loss, int* __restrict__ gcnt,
    float* __restrict__ embTf, unsigned short* __restrict__ embTbf,
    const float* __restrict__ z, float* __restrict__ r2out) {
  __shared__ float t[64][65];
  __shared__ float zc[64][36];
  __shared__ float pmm[64][2][4];
  const int tid = threadIdx.x;
  if (blockIdx.x < 4) {
    // c2[k] = sequential fp32 sum of fl(e[d,k]^2)  [verified round 3]
    int k = blockIdx.x * NTHREADS + tid;
    float s = 0.f;
    for (int d = 0; d < EMB_DIM; ++d) {
      float v = emb[d * NUM_EMB + k];
      s = __fadd_rn(s, __fmul_rn(v, v));
    }
    cvec[k] = s;
    hist[k] = 0;
    if (k == 0) { *loss = 0.f; *gcnt = 0; }
  } else if (blockIdx.x < 68) {
    // transpose emb [256][1024] -> embTf fp32 [1024][256] + embTbf bf16
    const int b = blockIdx.x - 4;
    const int kt = b & 15, dt = b >> 4;
    #pragma unroll
    for (int it = 0; it < 16; ++it) {
      int i = tid + it * NTHREADS, r = i >> 6, c = i & 63;
      t[r][c] = emb[(dt * 64 + r) * NUM_EMB + kt * 64 + c];
    }
    __syncthreads();
    #pragma unroll
    for (int it = 0; it < 16; ++it) {
      int i = tid + it * NTHREADS, r = i >> 6, c = i & 63;
      float v = t[c][r];
      embTf[(kt * 64 + r) * EMB_DIM + dt * 64 + c] = v;
      embTbf[(kt * 64 + r) * EMB_DIM + dt * 64 + c] = f2bf(v);
    }
  } else {
    // r2[n] = numpy pairwise fp32 sum of z[n,:]**2  [verified round 3, verbatim body]
    const int n0 = (blockIdx.x - 68) * 64;
    const float* zrow = z + (size_t)n0 * EMB_DIM;
    const int prow = tid >> 2, pm = tid & 3;
    float racc[2][2] = {{0.f, 0.f}, {0.f, 0.f}};
    for (int dc = 0; dc < 8; ++dc) {
      __syncthreads();
      #pragma unroll
      for (int it = 0; it < 2; ++it) {
        int i = tid + it * NTHREADS, row = i >> 3, f4 = i & 7;
        *(float4*)(&zc[row][f4 * 4]) = *(const float4*)(zrow + row * EMB_DIM + dc * 32 + f4 * 4);
      }
      __syncthreads();
      const int half = dc >> 2;
      #pragma unroll
      for (int q = 0; q < 4; ++q)
        #pragma unroll
        for (int jj = 0; jj < 2; ++jj) {
          float v = zc[prow][(pm * 2 + jj) + 8 * q];
          racc[half][jj] = __fadd_rn(racc[half][jj], __fmul_rn(v, v));
        }
    }
    pmm[prow][0][pm] = __fadd_rn(racc[0][0], racc[0][1]);
    pmm[prow][1][pm] = __fadd_rn(racc[1][0], racc[1][1]);
    __syncthreads();
    if (tid < 64) {
      float h0 = __fadd_rn(__fadd_rn(pmm[tid][0][0], pmm[tid][0][1]),
                           __fadd_rn(pmm[tid][0][2], pmm[tid][0][3]));
      float h1 = __fadd_rn(__fadd_rn(pmm[tid][1][0], pmm[tid][1][1]),
                           __fadd_rn(pmm[tid][1][2], pmm[tid][1][3]));
      r2out[n0 + tid] = __fadd_rn(h0, h1);
    }
  }
}

// bf16 MFMA approx-distance sweep + candidate capture.
// Round-7 structure: 128 rows x 1024 codes per block, 512 threads (8 waves),
// grid=512 -> TWO independent blocks per CU. Rationale: rounds 4-6 proved the
// 1-block/CU version is phase-locked (VALU 23% + MFMA 15% + LDS ~20% sum with
// no overlap); two independent barrier groups let one block's capture (VALU)
// overlap the other's MFMA phase.
//  - wave tile stays square 64x64 (2rg x 4cg, acc[4][4]) -> LDS/MFMA unchanged
//  - zc[128][256] 64KB + single-buffer Bl 16KB = 80KB = exactly 2 blocks/CU
//  - single-buffer B: 2 lgkm barriers/kc (rounds 1/4/5: barrier count ~free)
//  - 2-deep register prefetch (pa/pb) rides across lgkm-only barriers
//  - capture overlays Bl (trivially free: chunk consumed, next write after)
__global__ __launch_bounds__(MTHREADS, 4) void vq_mfma(
    const float* __restrict__ z, const unsigned short* __restrict__ embTbf,
    const float* __restrict__ cvec, unsigned long long* __restrict__ slots,
    int* __restrict__ gcnt, unsigned int* __restrict__ glist,
    int* __restrict__ grm) {
  __shared__ unsigned short zc[MROWS][256];  // 65536 B, 16B-unit XOR swizzle
  __shared__ unsigned short Bl[8192];        // 16384 B single buffer (256 codes x 32 k)

  // capture-scratch overlay on Bl (4096 ints):
  //   [0..127] rowminb, [128] lcnt, [129] lbase, [130] lcount, [131..4095] llist
  int* caps = (int*)&Bl[0];
  unsigned int* llist = (unsigned int*)caps + 131;   // LLCAP = 4096-131 = 3965

  const int tid = threadIdx.x;               // 0..511
  const int lane = tid & 63, wave = tid >> 6; // 8 waves
  const int quad = lane >> 4, l15 = lane & 15;
  const int rg = wave >> 2, cg = wave & 3;   // 2 row-groups x 4 code-groups
  const int n0 = blockIdx.x * MROWS;

  if (tid < MROWS) {
    grm[n0 + tid] = 0x7F000000;              // block-private rows; same-thread order
    slots[n0 + tid] = ~0ULL;
  }

  // stage A: 128 rows z fp32 -> bf16 swizzled LDS (coalesced, conflict-free)
  #pragma unroll
  for (int it = 0; it < 8; ++it) {
    int g = tid + it * MTHREADS, row = g >> 5, u = g & 31;
    const float* src = z + (size_t)(n0 + row) * EMB_DIM + u * 8;
    float4 a = *(const float4*)src;
    float4 b = *(const float4*)(src + 4);
    uint4 w;
    w.x = ((unsigned)f2bf(a.y) << 16) | f2bf(a.x);
    w.y = ((unsigned)f2bf(a.w) << 16) | f2bf(a.z);
    w.z = ((unsigned)f2bf(b.y) << 16) | f2bf(b.x);
    w.w = ((unsigned)f2bf(b.w) << 16) | f2bf(b.z);
    *(uint4*)(&zc[row][(u ^ (row & 7)) * 8]) = w;
  }

  // B staging: 16KB chunk = 1024 x 16B units; 512 threads -> 2 units each
  // (codes bn and bn+128). Swizzle note: ((bn+128)>>1)&3 == (bn>>1)&3, so
  // unitB = unitA + 512.
  const int bn = tid >> 2, bseg = tid & 3;
  const size_t bofsA = (size_t)bn * EMB_DIM + (size_t)bseg * 8;
  const size_t bofsB = (size_t)(bn + 128) * EMB_DIM + (size_t)bseg * 8;
  const int bunitA = bn * 4 + (bseg ^ ((bn >> 1) & 3));
  const int bunitB = bunitA + 512;
  // LDS read units (code local to tile; constant across j and kc)
  int bidx[4];
  #pragma unroll
  for (int ct = 0; ct < 4; ++ct) {
    int cn = cg * 64 + ct * 16 + l15;
    bidx[ct] = (cn * 4 + (quad ^ ((cn >> 1) & 3))) * 8;
  }

  uint4 pa = *(const uint4*)(embTbf + bofsA);            // chunk 0 halves
  uint4 pb = *(const uint4*)(embTbf + bofsB);

  for (int j = 0; j < 4; ++j) {               // 4 j-tiles x 256 codes
    f32x4 acc[4][4];
    #pragma unroll
    for (int rt = 0; rt < 4; ++rt)
      #pragma unroll
      for (int ct = 0; ct < 4; ++ct)
        acc[rt][ct] = (f32x4){0.f, 0.f, 0.f, 0.f};
    float c2r[4];
    #pragma unroll
    for (int ct = 0; ct < 4; ++ct)
      c2r[ct] = cvec[j * 256 + cg * 64 + ct * 16 + l15] + 1.0f;

    for (int kc = 0; kc < 8; ++kc) {
      const int c = j * 8 + kc;
      BAR_LGKM();                            // Bl safe to overwrite (prev readers /
                                             // capture flush done; also orders zc
                                             // staging before first reads)
      *(uint4*)(&Bl[(size_t)bunitA * 8]) = pa;
      *(uint4*)(&Bl[(size_t)bunitB * 8]) = pb;
      BAR_LGKM();                            // chunk c visible
      if (c + 1 < 32) {                      // issue next chunk load during MFMA phase
        const unsigned short* srcp = embTbf +
            (size_t)((c + 1) >> 3) * 65536 + (size_t)((c + 1) & 7) * 32;
        pa = *(const uint4*)(srcp + bofsA);
        pb = *(const uint4*)(srcp + bofsB);
      }
      bf16x8 av[4], bv[4];
      #pragma unroll
      for (int rt = 0; rt < 4; ++rt) {
        int row = rg * 64 + rt * 16 + l15;
        av[rt] = *(const bf16x8*)(&zc[row][((kc * 4 + quad) ^ (l15 & 7)) * 8]);
      }
      #pragma unroll
      for (int ct = 0; ct < 4; ++ct)
        bv[ct] = *(const bf16x8*)(&Bl[(size_t)bidx[ct]]);
      #pragma unroll
      for (int rt = 0; rt < 4; ++rt)
        #pragma unroll
        for (int ct = 0; ct < 4; ++ct)
          acc[rt][ct] = __builtin_amdgcn_mfma_f32_16x16x32_bf16(av[rt], bv[ct], acc[rt][ct], 0, 0, 0);
    }
    // ---- capture phase: overlays Bl (chunk 8j+7 consumed; next write gated by
    //      next kc=0's safe-barrier, after this phase's last barrier)
    BAR_LGKM();                               // all kc=7 Bl reads complete
    if (tid < MROWS) caps[tid] = 0x7F000000;  // rowminb init
    if (tid == 0) caps[128] = 0;              // lcnt
    BAR_LGKM();

    // per-wave 64-code row-min -> LDS atomicMin (tight, block-wide)
    #pragma unroll
    for (int rt = 0; rt < 4; ++rt)
      #pragma unroll
      for (int reg = 0; reg < 4; ++reg) {
        float m = 1e30f;
        #pragma unroll
        for (int ct = 0; ct < 4; ++ct) {
          float d = fmaf(-2.f, acc[rt][ct][reg], c2r[ct]);
          m = fminf(m, d);
        }
        #pragma unroll
        for (int off = 1; off < 16; off <<= 1)
          m = fminf(m, __shfl_xor(m, off));
        if (l15 == 0)
          atomicMin(&caps[rg * 64 + rt * 16 + quad * 4 + reg], __float_as_int(m));
      }
    BAR_LGKM();                               // rowminb final for this j

    // merge with global running min across j (returning atomicMin)
    if (tid < MROWS) {
      int lm = caps[tid];
      int old = atomicMin(&grm[n0 + tid], lm);
      caps[tid] = lm < old ? lm : old;
    }
    BAR_LGKM();                               // merged bound visible

    // capture candidates within EPSF of running min -> LDS llist
    // (ballot-aggregated: one LDS atomic per wave per hit-group)
    #pragma unroll
    for (int rt = 0; rt < 4; ++rt)
      #pragma unroll
      for (int reg = 0; reg < 4; ++reg) {
        int rowl = rg * 64 + rt * 16 + quad * 4 + reg;
        float fmin = __int_as_float(caps[rowl]);
        #pragma unroll
        for (int ct = 0; ct < 4; ++ct) {
          float d = fmaf(-2.f, acc[rt][ct][reg], c2r[ct]);
          bool pred = (d <= fmin + EPSF);
          unsigned long long msk = __ballot(pred);
          if (msk) {
            int leader = (int)(__ffsll((long long)msk) - 1);
            int cnt = (int)__popcll(msk);
            int base0 = 0;
            if (lane == leader) base0 = atomicAdd(&caps[128], cnt);
            base0 = __shfl(base0, leader);
            if (pred) {
              int id = base0 + (int)__popcll(msk & ((1ULL << lane) - 1ULL));
              int k = j * 256 + cg * 64 + ct * 16 + l15;
              if (id < LLCAP)
                llist[id] = ((unsigned)(n0 + rowl) << 10) | (unsigned)k;
            }
          }
        }
      }
    BAR_LGKM();
    if (tid == 0) {
      int c = caps[128]; if (c > LLCAP) c = LLCAP;
      caps[130] = c;
      caps[129] = atomicAdd(gcnt, c);          // ONE global atomic per block per j
    }
    BAR_LGKM();
    {
      int cnt = caps[130], base = caps[129];
      for (int i = tid; i < cnt; i += MTHREADS)
        if (base + i < GCAP) glist[base + i] = llist[i];
    }
    // next j's kc=0 safe-barrier orders llist reads before Bl overwrite
  }
}

// exact numpy-fp32 re-evaluation of captured pairs [arithmetic verified round 3]
__global__ __launch_bounds__(NTHREADS) void vq_refine(
    const float* __restrict__ z, const float* __restrict__ embTf,
    const float* __restrict__ r2, const float* __restrict__ cvec,
    const int* __restrict__ gcnt, const unsigned int* __restrict__ glist,
    unsigned long long* __restrict__ slots) {
  int n = *gcnt; if (n > GCAP) n = GCAP;
  for (int i = blockIdx.x * NTHREADS + threadIdx.x; i < n;
       i += gridDim.x * NTHREADS) {
    unsigned e = glist[i];
    int grow = (int)(e >> 10), k = (int)(e & 1023);
    const float* zr = z + (size_t)grow * EMB_DIM;
    const float* er = embTf + (size_t)k * EMB_DIM;
    float s = 0.f;
    for (int d = 0; d < EMB_DIM; ++d)       // strict sequential-d fmaf chain
      s = fmaf(zr[d], er[d], s);
    float dist = __fsub_rn(__fadd_rn(r2[grow], cvec[k]), __fmul_rn(2.0f, s));
    unsigned long long key =
        ((unsigned long long)__float_as_uint(dist) << 32) | (unsigned)k;
    atomicMin(&slots[grow], key);
  }
}

// final index + gather + straight-through write + loss + histogram
__global__ __launch_bounds__(NTHREADS) void vq_epi(
    const float* __restrict__ z, const float* __restrict__ embTf,
    const unsigned long long* __restrict__ slots,
    float* __restrict__ out, int* __restrict__ hist, float* __restrict__ loss) {
  __shared__ int ks[64];
  __shared__ float wsum[4];
  const int tid = threadIdx.x;
  const int n0 = blockIdx.x * 64;
  const float* zrow = z + (size_t)n0 * EMB_DIM;
  if (tid < 64) {
    int k = (int)(slots[n0 + tid] & 1023ULL);
    ks[tid] = k;
    out[OFF_IDX + n0 + tid] = (float)k;
    atomicAdd(&hist[k], 1);
  }
  __syncthreads();
  float sumsq = 0.f;
  #pragma unroll
  for (int it = 0; it < 16; ++it) {
    int g = tid + it * NTHREADS;
    int row = g >> 6;
    int d = (g & 63) * 4;
    int k = ks[row];
    float4 zv = *(const float4*)(zrow + row * EMB_DIM + d);
    float4 q = *(const float4*)(embTf + (size_t)k * EMB_DIM + d);
    float4 df;
    df.x = q.x - zv.x; df.y = q.y - zv.y; df.z = q.z - zv.z; df.w = q.w - zv.w;
    sumsq = fmaf(df.x, df.x, sumsq);
    sumsq = fmaf(df.y, df.y, sumsq);
    sumsq = fmaf(df.z, df.z, sumsq);
    sumsq = fmaf(df.w, df.w, sumsq);
    *(float4*)(out + (size_t)(n0 + row) * EMB_DIM + d) = q;
  }
  #pragma unroll
  for (int off = 32; off > 0; off >>= 1) sumsq += __shfl_down(sumsq, off);
  if ((tid & 63) == 0) wsum[tid >> 6] = sumsq;
  __syncthreads();
  if (tid == 0) atomicAdd(loss, wsum[0] + wsum[1] + wsum[2] + wsum[3]);
}

__global__ __launch_bounds__(NTHREADS) void vq_finalize(
    const int* __restrict__ hist, const float* __restrict__ loss,
    float* __restrict__ out) {
  __shared__ float ws[4];
  int tid = threadIdx.x;
  float s = 0.f;
  for (int k = tid; k < NUM_EMB; k += NTHREADS) {
    float p = (float)hist[k] * (1.0f / 65536.0f);
    s += p * logf(p + 1e-10f);
  }
  #pragma unroll
  for (int off = 32; off > 0; off >>= 1) s += __shfl_down(s, off);
  if ((tid & 63) == 0) ws[tid >> 6] = s;
  __syncthreads();
  if (tid == 0) {
    float tot = ws[0] + ws[1] + ws[2] + ws[3];
    float vq = *loss * (1.0f / 16777216.0f);
    out[OFF_VQ + 0] = vq;
    out[OFF_VQ + 1] = 0.25f * vq;
    out[OFF_VQ + 2] = expf(-tot);
  }
}

extern "C" void kernel_launch(void* const* d_in, const int* in_sizes, int n_in,
                              void* d_out, int out_size, void* d_ws, size_t ws_size,
                              hipStream_t stream) {
  const float* z   = (const float*)d_in[0];
  const float* emb = (const float*)d_in[1];
  float* out = (float*)d_out;
  char* ws = (char*)d_ws;
  float* cvec   = (float*)(ws + WS_C2);
  int*   hist   = (int*)(ws + WS_HIST);
  float* loss   = (float*)(ws + WS_LOSS);
  int*   gcnt   = (int*)(ws + WS_GCNT);
  float* r2     = (float*)(ws + WS_R2);
  unsigned long long* slots = (unsigned long long*)(ws + WS_SLOT);
  float* embTf  = (float*)(ws + WS_ETF);
  unsigned short* embTbf = (unsigned short*)(ws + WS_ETB);
  int*   grm    = (int*)(ws + WS_RMIN);
  unsigned int* glist = (unsigned int*)(ws + WS_GLIST);

  vq_pt<<<1092, NTHREADS, 0, stream>>>(emb, cvec, hist, loss, gcnt, embTf, embTbf, z, r2);
  vq_mfma<<<NROWS / MROWS, MTHREADS, 0, stream>>>(z, embTbf, cvec, slots, gcnt, glist, grm);
  vq_refine<<<512, NTHREADS, 0, stream>>>(z, embTf, r2, cvec, gcnt, glist, slots);
  vq_epi<<<NROWS / 64, NTHREADS, 0, stream>>>(z, embTf, slots, out, hist, loss);
  vq_finalize<<<1, NTHREADS, 0, stream>>>(hist, loss, out);
}